// Round 12
// baseline (704.491 us; speedup 1.0000x reference)
//
#include <hip/hip_runtime.h>
#include <math.h>

// GATNet: 2-layer GAT, N=100000 nodes, E=3200000 edges (+N self loops).
// Outputs (flat concat): h2 [N,2], alpha1 [E+N,8], alpha2 [E+N,1], fp32.
//
// CSR node-centric, NO fp32 atomics, h1 never materialized, DEFERRED-MAX
// single-pass softmax (scores are O(3); exp clamped at 80 consistently).
// CSR build is a LOCALITY-AWARE two-phase binned counting sort:
//   bucket b = dst>>4 (16 nodes/bucket, 6250 buckets; N = 6250*16 exactly).
//   Bucket region in any dst-sorted layout is [rowstart[16b], rowstart[16b+16])
//   — no extra scan needed.
//   k_binfill: append packed (src<<4 | dst&15) int to bucket region (hot
//              region heads -> writebacks merge; kills the 200MB write
//              amplification rocprof showed for the direct scatter).
//   k_fill2  : one block per bucket; LDS fill counters (no global atomics);
//              scatter src into csr_src within a ~2KB L1-resident window.

#define N_NODES 100000
#define N_EDGES 3200000
#define E_TOT   (N_EDGES + N_NODES)
#define NBUCK   (N_NODES / 16)             // 6250 (exact)
#define NEG_SLOPE 0.2f
#define GAT_EPS 1e-16f
#define RCLAMP 80.0f
#define SCAN_NBLK ((N_NODES + 255) / 256)   // 391

__device__ __forceinline__ float lrelu(float r) {
    return r > 0.f ? r : NEG_SLOPE * r;
}

// ---------------- node-level prep, layer 1 ----------------
__global__ void k_node1(const float* __restrict__ x,
                        const float* __restrict__ W1,    // [2][64]
                        const float* __restrict__ as1,   // [8][8] flat
                        const float* __restrict__ ad1,   // [8][8] flat
                        float* __restrict__ asp,         // [N][12] {asrc[8],x0,x1,pad2}
                        float* __restrict__ adp,         // [N][16] {adst[8],inv[8]}
                        int* __restrict__ cnt,
                        int* __restrict__ bfill)
{
    int n = blockIdx.x * blockDim.x + threadIdx.x;
    if (n >= N_NODES) return;
    float x0 = x[2*n+0], x1 = x[2*n+1];
    #pragma unroll
    for (int h = 0; h < 8; ++h) {
        float s = 0.f, d = 0.f;
        #pragma unroll
        for (int c = 0; c < 8; ++c) {
            int j = h*8 + c;
            float v = fmaf(x0, W1[j], x1 * W1[64 + j]);
            s = fmaf(v, as1[j], s);
            d = fmaf(v, ad1[j], d);
        }
        asp[(size_t)n*12+h] = s;
        adp[(size_t)n*16+h] = d;
    }
    asp[(size_t)n*12+8] = x0;
    asp[(size_t)n*12+9] = x1;
    cnt[n] = 0;
    if (n < NBUCK) bfill[n] = 0;
}

// ---------------- CSR build ----------------
__global__ void k_hist(const int* __restrict__ ei, int* __restrict__ cnt)
{
    int e = blockIdx.x * blockDim.x + threadIdx.x;
    if (e >= E_TOT) return;
    int d = (e < N_EDGES) ? ei[N_EDGES + e] : e - N_EDGES;
    atomicAdd(&cnt[d], 1);
}

__global__ void k_scan_partial(const int* __restrict__ cnt, int* __restrict__ part)
{
    __shared__ int s[256];
    int t = threadIdx.x;
    int i = blockIdx.x * 256 + t;
    s[t] = (i < N_NODES) ? cnt[i] : 0;
    __syncthreads();
    #pragma unroll
    for (int off = 128; off > 0; off >>= 1) {
        if (t < off) s[t] += s[t + off];
        __syncthreads();
    }
    if (t == 0) part[blockIdx.x] = s[0];
}

__global__ void k_scan_single(const int* __restrict__ part, int* __restrict__ partpre)
{
    __shared__ int s[512];
    int t = threadIdx.x;
    int c = (t < SCAN_NBLK) ? part[t] : 0;
    s[t] = c;
    __syncthreads();
    for (int off = 1; off < 512; off <<= 1) {
        int v = (t >= off) ? s[t - off] : 0;
        __syncthreads();
        s[t] += v;
        __syncthreads();
    }
    if (t < SCAN_NBLK) partpre[t] = s[t] - c;   // exclusive
}

__global__ void k_scan_final(const int* __restrict__ cnt,
                             const int* __restrict__ partpre,
                             int* __restrict__ rowstart)
{
    __shared__ int s[256];
    int t = threadIdx.x;
    int i = blockIdx.x * 256 + t;
    int c = (i < N_NODES) ? cnt[i] : 0;
    s[t] = c;
    __syncthreads();
    for (int off = 1; off < 256; off <<= 1) {
        int v = (t >= off) ? s[t - off] : 0;
        __syncthreads();
        s[t] += v;
        __syncthreads();
    }
    if (i < N_NODES) rowstart[i] = partpre[blockIdx.x] + s[t] - c;
}

// Phase A: append packed (src<<4 | dst&15) into the dst-bucket's region.
__global__ void k_binfill(const int* __restrict__ ei,
                          const int* __restrict__ rowstart,
                          int* __restrict__ bfill,
                          int* __restrict__ bins)
{
    int e = blockIdx.x * blockDim.x + threadIdx.x;
    if (e >= E_TOT) return;
    int s, d;
    if (e < N_EDGES) { s = ei[e]; d = ei[N_EDGES + e]; } else { s = d = e - N_EDGES; }
    int b = d >> 4;
    int base = rowstart[b << 4];            // bucket region start
    int slot = atomicAdd(&bfill[b], 1);
    bins[base + slot] = (s << 4) | (d & 15);
}

// Phase B: one block per bucket; LDS fill counters; L1-local scatter.
__global__ void __launch_bounds__(256) k_fill2(
        const int* __restrict__ bins,
        const int* __restrict__ rowstart,
        int* __restrict__ csr_src)
{
    __shared__ int lfill[16];
    __shared__ int lrow[16];
    int b = blockIdx.x;
    int t = threadIdx.x;
    int node0 = b << 4;
    if (t < 16) {
        lfill[t] = 0;
        lrow[t] = rowstart[node0 + t];
    }
    __syncthreads();
    int base = lrow[0];
    int end = (node0 + 16 < N_NODES) ? rowstart[node0 + 16] : E_TOT;
    for (int i = base + t; i < end; i += 256) {
        int v = bins[i];
        int dl = v & 15;
        int pos = lrow[dl] + atomicAdd(&lfill[dl], 1);
        csr_src[pos] = v >> 4;
    }
}

// ------ layer 1: wave-per-node, lane=(slot,head), single-pass softmax ------
__global__ void __launch_bounds__(256) k_gat1(
        const int* __restrict__ rowstart,
        const int* __restrict__ cnt,
        const int* __restrict__ csr_src,
        const float* __restrict__ asp,    // [N][12] {asrc[8], x0, x1, pad}
        const float* __restrict__ W1,     // [2][64]
        float* __restrict__ adp,          // [N][16] {adst[8], inv[8]}
        const float* __restrict__ b1,     // [64]
        const float* __restrict__ W2,     // [64][2]
        const float* __restrict__ as2,    // [2]
        const float* __restrict__ ad2,    // [2]
        float4* __restrict__ nd2,         // [N] {h2p0, h2p1, asrc2, adst2}
        float* __restrict__ asrc2)        // [N]
{
    int wave = threadIdx.x >> 6;
    int lane = threadIdx.x & 63;
    int n = blockIdx.x * 4 + wave;
    if (n >= N_NODES) return;
    int h = lane & 7;            // head
    int j = lane >> 3;           // edge slot

    float adst_h = adp[(size_t)n*16 + h];
    int start = rowstart[n];
    int deg   = cnt[n];          // >= 1 (self-loop)

    // depth-1 software pipeline over edge slots j, j+8, j+16, ...
    int idx = j;
    int sP = csr_src[start + min(idx, deg-1)];
    float  aP = asp[(size_t)sP*12 + h];
    float2 xP = *(const float2*)(asp + (size_t)sP*12 + 8);

    float den = 0.f, S0 = 0.f, S1 = 0.f;
    int iters = (deg + 7) >> 3;
    for (int i = 0; i < iters; ++i) {
        float a = aP; float2 xs = xP;
        int curIdx = idx;
        idx += 8;
        int cl = min(idx, deg-1);
        sP = csr_src[start + cl];
        aP = asp[(size_t)sP*12 + h];
        xP = *(const float2*)(asp + (size_t)sP*12 + 8);
        float r = fminf(lrelu(a + adst_h), RCLAMP);
        float p = (curIdx < deg) ? __expf(r) : 0.f;
        den += p;
        S0 = fmaf(p, xs.x, S0);
        S1 = fmaf(p, xs.y, S1);
    }
    // butterfly reduce over slot bits (lane bits 3..5)
    #pragma unroll
    for (int off = 8; off <= 32; off <<= 1) {
        den += __shfl_xor(den, off, 64);
        S0  += __shfl_xor(S0,  off, 64);
        S1  += __shfl_xor(S1,  off, 64);
    }
    float invden = 1.f / (den + GAT_EPS);
    if (j == 0) adp[(size_t)n*16 + 8 + h] = invden;  // lanes 0-7: 32B coalesced

    // epilogue: this lane owns channel cI = h*8 + j
    int cI = h*8 + j;
    float w0 = W1[cI], w1 = W1[64 + cI];
    float v = fmaf(w0, S0, w1 * S1) * invden + b1[cI];
    v = v > 0.f ? v : expm1f(v);                    // ELU
    float c0 = v * W2[2*cI+0];
    float c1 = v * W2[2*cI+1];
    #pragma unroll
    for (int off = 1; off <= 32; off <<= 1) {
        c0 += __shfl_xor(c0, off, 64);
        c1 += __shfl_xor(c1, off, 64);
    }
    if (lane == 0) {
        float s2 = fmaf(c0, as2[0], c1 * as2[1]);
        float d2 = fmaf(c0, ad2[0], c1 * ad2[1]);
        nd2[n] = make_float4(c0, c1, s2, d2);
        asrc2[n] = s2;
    }
}

// ------ layer 2: 16 lanes per node, single-pass softmax (1 head, 2 ch) -----
__global__ void __launch_bounds__(256) k_gat2(
        const int* __restrict__ rowstart,
        const int* __restrict__ cnt,
        const int* __restrict__ csr_src,
        const float4* __restrict__ nd2,   // [N] {h2p0, h2p1, asrc2, adst2}
        const float* __restrict__ b2,     // [2]
        float* __restrict__ out_h2,       // [N][2]
        float2* __restrict__ pk2)         // [N] {adst2, invden}
{
    int t = threadIdx.x & 15;             // edge slot within group
    int n = blockIdx.x * 16 + (threadIdx.x >> 4);
    if (n >= N_NODES) return;
    float ad = nd2[n].w;
    int start = rowstart[n];
    int deg   = cnt[n];

    int idx = t;
    float4 qP = nd2[csr_src[start + min(idx, deg-1)]];

    float den = 0.f, a0 = 0.f, a1 = 0.f;
    int iters = (deg + 15) >> 4;
    for (int i = 0; i < iters; ++i) {
        float4 q = qP;
        int curIdx = idx;
        idx += 16;
        qP = nd2[csr_src[start + min(idx, deg-1)]];
        float r = fminf(lrelu(q.z + ad), RCLAMP);
        float p = (curIdx < deg) ? __expf(r) : 0.f;
        den += p;
        a0 = fmaf(p, q.x, a0);
        a1 = fmaf(p, q.y, a1);
    }
    #pragma unroll
    for (int off = 1; off <= 8; off <<= 1) {
        den += __shfl_xor(den, off, 64);
        a0  += __shfl_xor(a0,  off, 64);
        a1  += __shfl_xor(a1,  off, 64);
    }
    float invden = 1.f / (den + GAT_EPS);
    if (t == 0) {
        out_h2[(size_t)n*2+0] = a0 * invden + b2[0];
        out_h2[(size_t)n*2+1] = a1 * invden + b2[1];
        pk2[n] = make_float2(ad, invden);
    }
}

// ---------------- alpha1 + alpha2 fused, edge order ----------------
__global__ void k_alpha(const int* __restrict__ ei,
                        const float* __restrict__ asp,    // [N][12]
                        const float* __restrict__ adp,    // [N][16]
                        const float* __restrict__ asrc2,
                        const float2* __restrict__ pk2,
                        float* __restrict__ out_a1,       // [E_TOT][8]
                        float* __restrict__ out_a2)       // [E_TOT]
{
    int e = blockIdx.x * blockDim.x + threadIdx.x;
    if (e >= E_TOT) return;
    int s, d;
    if (e < N_EDGES) { s = ei[e]; d = ei[N_EDGES + e]; } else { s = d = e - N_EDGES; }
    const float4* av = (const float4*)(asp + (size_t)s*12);
    const float4* pv = (const float4*)(adp + (size_t)d*16);
    float4 a0=av[0], a1=av[1];
    float4 b0=pv[0], b1=pv[1], i0=pv[2], i1=pv[3];
    float4 o0, o1;
    o0.x = __expf(fminf(lrelu(a0.x+b0.x), RCLAMP)) * i0.x;
    o0.y = __expf(fminf(lrelu(a0.y+b0.y), RCLAMP)) * i0.y;
    o0.z = __expf(fminf(lrelu(a0.z+b0.z), RCLAMP)) * i0.z;
    o0.w = __expf(fminf(lrelu(a0.w+b0.w), RCLAMP)) * i0.w;
    o1.x = __expf(fminf(lrelu(a1.x+b1.x), RCLAMP)) * i1.x;
    o1.y = __expf(fminf(lrelu(a1.y+b1.y), RCLAMP)) * i1.y;
    o1.z = __expf(fminf(lrelu(a1.z+b1.z), RCLAMP)) * i1.z;
    o1.w = __expf(fminf(lrelu(a1.w+b1.w), RCLAMP)) * i1.w;
    float4* ao = (float4*)(out_a1 + (size_t)e*8);
    ao[0] = o0; ao[1] = o1;

    float2 pk = pk2[d];                  // {adst2, invden}
    float r = fminf(lrelu(asrc2[s] + pk.x), RCLAMP);
    out_a2[e] = __expf(r) * pk.y;
}

extern "C" void kernel_launch(void* const* d_in, const int* in_sizes, int n_in,
                              void* d_out, int out_size, void* d_ws, size_t ws_size,
                              hipStream_t stream)
{
    const float* x   = (const float*)d_in[0];
    const int*   ei  = (const int*)d_in[1];
    const float* W1  = (const float*)d_in[2];
    const float* as1 = (const float*)d_in[3];
    const float* ad1 = (const float*)d_in[4];
    const float* b1  = (const float*)d_in[5];
    const float* W2  = (const float*)d_in[6];
    const float* as2 = (const float*)d_in[7];
    const float* ad2 = (const float*)d_in[8];
    const float* b2  = (const float*)d_in[9];

    float* out_h2 = (float*)d_out;                       // [N,2]
    float* out_a1 = out_h2 + (size_t)N_NODES * 2;        // [E_TOT,8]
    float* out_a2 = out_a1 + (size_t)E_TOT * 8;          // [E_TOT,1]

    char* ws = (char*)d_ws;
    float4* nd2   = (float4*)ws; ws += (size_t)N_NODES*16;      // 16B aligned
    int* bins     = (int*)ws;    ws += (size_t)E_TOT*4;
    float* asp    = (float*)ws;  ws += (size_t)N_NODES*12*4;    // 16B aligned
    float* adp    = (float*)ws;  ws += (size_t)N_NODES*16*4;
    float2* pk2   = (float2*)ws; ws += (size_t)N_NODES*8;
    float* asrc2  = (float*)ws;  ws += (size_t)N_NODES*4;
    int* cnt      = (int*)ws;    ws += (size_t)N_NODES*4;
    int* bfill    = (int*)ws;    ws += (size_t)NBUCK*4;
    int* rowstart = (int*)ws;    ws += (size_t)(N_NODES+1)*4;
    int* part     = (int*)ws;    ws += (size_t)512*4;
    int* partpre  = (int*)ws;    ws += (size_t)512*4;
    int* csr_src  = (int*)ws;    ws += (size_t)E_TOT*4;

    dim3 blk(256);
    int gN = (N_NODES + 255) / 256;
    int gE = (E_TOT + 255) / 256;

    k_node1<<<gN, blk, 0, stream>>>(x, W1, as1, ad1, asp, adp, cnt, bfill);
    k_hist<<<gE, blk, 0, stream>>>(ei, cnt);
    k_scan_partial<<<SCAN_NBLK, blk, 0, stream>>>(cnt, part);
    k_scan_single<<<1, 512, 0, stream>>>(part, partpre);
    k_scan_final<<<SCAN_NBLK, blk, 0, stream>>>(cnt, partpre, rowstart);
    k_binfill<<<gE, blk, 0, stream>>>(ei, rowstart, bfill, bins);
    k_fill2<<<NBUCK, blk, 0, stream>>>(bins, rowstart, csr_src);
    k_gat1<<<(N_NODES + 3) / 4, blk, 0, stream>>>(rowstart, cnt, csr_src, asp,
            W1, adp, b1, W2, as2, ad2, nd2, asrc2);
    k_gat2<<<(N_NODES + 15) / 16, blk, 0, stream>>>(rowstart, cnt, csr_src, nd2,
            b2, out_h2, pk2);
    k_alpha<<<gE, blk, 0, stream>>>(ei, asp, adp, asrc2, pk2, out_a1, out_a2);
}